// Round 13
// baseline (433.168 us; speedup 1.0000x reference)
//
#include <hip/hip_runtime.h>
#include <hip/hip_bf16.h>

typedef unsigned short ushort_t;
typedef __attribute__((ext_vector_type(8))) short short8;
typedef __attribute__((ext_vector_type(8))) __bf16 bf16x8;
typedef __attribute__((ext_vector_type(4))) float f32x4;

#define LQS 4096
#define LKS 4096
#define NH 16
#define HD 64
#define DIN 1024
#define KVB 64
static constexpr float TAU_S = 0.125f;  // 1/sqrt(64)
static constexpr float LOG2E = 1.4426950408889634f;

__device__ __forceinline__ float exp2_fast(float x) { return __builtin_amdgcn_exp2f(x); }
__device__ __forceinline__ float log2_fast(float x) { return __builtin_amdgcn_logf(x); }

__device__ __forceinline__ ushort_t f32_to_bf16(float x) {
  union { float f; unsigned u; } v; v.f = x;
  unsigned r = v.u + 0x7FFF + ((v.u >> 16) & 1);
  return (ushort_t)(r >> 16);
}

__device__ __forceinline__ unsigned cvt_pk_bf16(float a, float b) {
  unsigned r;
  asm volatile("v_cvt_pk_bf16_f32 %0, %1, %2" : "=v"(r) : "v"(a), "v"(b));
  return r;
}

__device__ __forceinline__ void gld_lds16(const void* g, void* l) {
  __builtin_amdgcn_global_load_lds((const __attribute__((address_space(1))) void*)g,
                                   (__attribute__((address_space(3))) void*)l, 16, 0, 0);
}

__device__ __forceinline__ f32x4 mfma16(bf16x8 a, bf16x8 b, f32x4 c) {
  return __builtin_amdgcn_mfma_f32_16x16x32_bf16(a, b, c, 0, 0, 0);
}

// ---------------- batched convert f32 -> bf16 (8 elems/thread) ----------------
struct Cvt3 { const float* src[3]; ushort_t* dst[3]; };
__global__ void cvt_kernel(Cvt3 c) {
  const float* __restrict__ src = c.src[blockIdx.y];
  ushort_t* __restrict__ dst = c.dst[blockIdx.y];
  int i = (blockIdx.x * 256 + threadIdx.x) * 8;
  float4 a = *(const float4*)(src + i);
  float4 b = *(const float4*)(src + i + 4);
  union { unsigned w[4]; short8 s; } o;
  o.w[0] = cvt_pk_bf16(a.x, a.y);
  o.w[1] = cvt_pk_bf16(a.z, a.w);
  o.w[2] = cvt_pk_bf16(b.x, b.y);
  o.w[3] = cvt_pk_bf16(b.z, b.w);
  *(short8*)(dst + i) = o.s;
}

// ---------------- combine PV partial sums -> ctx bf16 ----------------
__global__ void combine_ctx(const float* __restrict__ p0, const float* __restrict__ p1,
                            ushort_t* __restrict__ ctx) {
  int i = (blockIdx.x * 256 + threadIdx.x) * 8;
  float4 a0 = *(const float4*)(p0 + i);
  float4 b0 = *(const float4*)(p0 + i + 4);
  float4 a1 = *(const float4*)(p1 + i);
  float4 b1 = *(const float4*)(p1 + i + 4);
  union { unsigned w[4]; short8 s; } o;
  o.w[0] = cvt_pk_bf16(a0.x + a1.x, a0.y + a1.y);
  o.w[1] = cvt_pk_bf16(a0.z + a1.z, a0.w + a1.w);
  o.w[2] = cvt_pk_bf16(b0.x + b1.x, b0.y + b1.y);
  o.w[3] = cvt_pk_bf16(b0.z + b1.z, b0.w + b1.w);
  *(short8*)(ctx + i) = o.s;
}

// ---------------- batched transpose + convert W [1024][1024] f32 -> bf16 ----------------
struct TW4 { const float* W[4]; ushort_t* Wt[4]; };
__global__ void transpose_w(TW4 w) {
  const float* __restrict__ W = w.W[blockIdx.z];
  ushort_t* __restrict__ Wt = w.Wt[blockIdx.z];
  __shared__ float tile[64][65];
  const int t = threadIdx.x;
  const int k0 = blockIdx.y * 64, n0 = blockIdx.x * 64;
#pragma unroll
  for (int i = 0; i < 16; ++i) {
    int idx = i * 256 + t;
    int r = idx >> 6, c = idx & 63;
    tile[r][c] = W[(size_t)(k0 + r) * DIN + n0 + c];
  }
  __syncthreads();
#pragma unroll
  for (int i = 0; i < 16; ++i) {
    int idx = i * 256 + t;
    int r = idx >> 6, c = idx & 63;  // r: n-local, c: k-local
    Wt[(size_t)(n0 + r) * DIN + k0 + c] = f32_to_bf16(tile[c][r]);
  }
}

// ---------------- transpose vh [4096][16*64] -> vt [16][64][4096] ----------------
__global__ void transpose_v(const ushort_t* __restrict__ vh, ushort_t* __restrict__ vt) {
  __shared__ ushort_t tile[64][65];
  const int t = threadIdx.x;
  const int k0 = blockIdx.x * 64, h = blockIdx.y;
#pragma unroll
  for (int i = 0; i < 16; ++i) {
    int idx = i * 256 + t;
    int r = idx >> 6, c = idx & 63;  // r: k-local, c: x
    tile[r][c] = vh[(size_t)(k0 + r) * DIN + h * HD + c];
  }
  __syncthreads();
#pragma unroll
  for (int i = 0; i < 16; ++i) {
    int idx = i * 256 + t;
    int r = idx >> 6, c = idx & 63;  // r: x, c: k-local
    vt[((size_t)h * HD + r) * (size_t)LKS + k0 + c] = tile[c][r];
  }
}

// ---------------- NT GEMM (128x128, BK=64, 4 waves 2x2), XCD-swizzled 1D grid --------
struct Batch3 {
  const ushort_t* A[3];
  const ushort_t* Bt[3];
  const float* bias[3];
  void* C[3];
  float scale[3];
};
template <bool OUT_F32>
__launch_bounds__(256, 2)
__global__ void gemm_nt(Batch3 bt3) {
  const int bid = blockIdx.x;
  const int xcd = bid & 7, idx = bid >> 3;
  const int z = idx >> 5, rem = idx & 31;
  const int by = xcd * 4 + (rem >> 3), bx = rem & 7;
  const ushort_t* __restrict__ A = bt3.A[z];
  const ushort_t* __restrict__ Bt = bt3.Bt[z];
  const float* __restrict__ bias = bt3.bias[z];
  void* __restrict__ Cout = bt3.C[z];
  const float scale = bt3.scale[z];
  const int K = DIN, N = DIN;

  __shared__ __align__(16) ushort_t Alds[128 * 64];
  __shared__ __align__(16) ushort_t Blds[128 * 64];
  const int t = threadIdx.x, wave = t >> 6, lane = t & 63;
  const int l15 = lane & 15, lg = lane >> 4;
  const int m0 = by * 128, n0 = bx * 128;
  const int wr = wave >> 1, wc = wave & 1;
  f32x4 acc[4][4];
#pragma unroll
  for (int i = 0; i < 4; ++i)
#pragma unroll
    for (int j = 0; j < 4; ++j) acc[i][j] = (f32x4){0.f, 0.f, 0.f, 0.f};

  for (int tk = 0; tk < K / 64; ++tk) {
#pragma unroll
    for (int c = 0; c < 4; ++c) {
      int chunk = wave * 4 + c;
      int row = chunk * 8 + (lane >> 3);
      int ss = (lane & 7) ^ (row & 7);
      gld_lds16(A + (size_t)(m0 + row) * K + tk * 64 + ss * 8, (char*)Alds + chunk * 1024);
      gld_lds16(Bt + (size_t)(n0 + row) * K + tk * 64 + ss * 8, (char*)Blds + chunk * 1024);
    }
    __syncthreads();
#pragma unroll
    for (int kk = 0; kk < 2; ++kk) {
      bf16x8 a[4], b[4];
#pragma unroll
      for (int i = 0; i < 4; ++i) {
        int ra = wr * 64 + i * 16 + l15;
        a[i] = *(const bf16x8*)((const char*)Alds + ra * 128 + ((((kk * 4 + lg) << 4)) ^ ((ra & 7) << 4)));
        int rb = wc * 64 + i * 16 + l15;
        b[i] = *(const bf16x8*)((const char*)Blds + rb * 128 + ((((kk * 4 + lg) << 4)) ^ ((rb & 7) << 4)));
      }
#pragma unroll
      for (int mi = 0; mi < 4; ++mi)
#pragma unroll
        for (int ni = 0; ni < 4; ++ni)
          acc[mi][ni] = mfma16(a[mi], b[ni], acc[mi][ni]);
    }
    __syncthreads();
  }
#pragma unroll
  for (int ni = 0; ni < 4; ++ni) {
    int coln = n0 + wc * 64 + ni * 16 + l15;
    float bv = bias[coln];
#pragma unroll
    for (int mi = 0; mi < 4; ++mi) {
#pragma unroll
      for (int r = 0; r < 4; ++r) {
        int rowm = m0 + wr * 64 + mi * 16 + lg * 4 + r;
        float v = (acc[mi][ni][r] + bv) * scale;
        if (OUT_F32)
          ((float*)Cout)[(size_t)rowm * N + coln] = v;
        else
          ((ushort_t*)Cout)[(size_t)rowm * N + coln] = f32_to_bf16(v);
      }
    }
  }
}

// ---------------- rowsum kernel: quarter k-range, 4 blocks/CU ----------------
// grid 1024: xcd=bid&7, idx=bid>>3 (0..127); h=xcd*2+(idx>>6); rem=idx&63;
// q0=(rem>>2)*256; quarter=rem&3 -> k tiles [quarter*16, quarter*16+16).
// Wave owns 64 q-rows (4 groups). Writes rsbuf[quarter][h][q].
__launch_bounds__(256, 4)
__global__ void rowsum_kernel(const ushort_t* __restrict__ qh, const ushort_t* __restrict__ kh,
                              float* __restrict__ rsbuf) {
  __shared__ __align__(16) ushort_t Klds[2][KVB * 64];
  const int t = threadIdx.x, wave = t >> 6, lane = t & 63;
  const int l15 = lane & 15, lg = lane >> 4;
  const int bid = blockIdx.x;
  const int xcd = bid & 7, idx = bid >> 3;   // idx 0..127
  const int h = xcd * 2 + (idx >> 6);        // 2 heads per XCD
  const int rem = idx & 63;
  const int q0 = (rem >> 2) * 256;
  const int quarter = rem & 3;
  const int w0 = q0 + wave * 64;

  bf16x8 qa[4][2];
#pragma unroll
  for (int g = 0; g < 4; ++g) {
    const ushort_t* qp = qh + (size_t)(w0 + g * 16 + l15) * DIN + h * HD + lg * 8;
    qa[g][0] = *(const bf16x8*)(qp);
    qa[g][1] = *(const bf16x8*)(qp + 32);
  }

  const int srow8 = lane >> 3;
  const int sslot = (lane & 7);
  const int tk0 = quarter * 16;

#define STAGE_K1(tile, buf)                                                         \
  {                                                                                 \
    _Pragma("unroll") for (int c = 0; c < 2; ++c) {                                 \
      int chunk = wave * 2 + c;                                                     \
      int row = chunk * 8 + srow8;                                                  \
      int ss = sslot ^ (row & 7);                                                   \
      gld_lds16(kh + (size_t)((tile) * KVB + row) * DIN + h * HD + ss * 8,          \
                (char*)Klds[buf] + chunk * 1024);                                   \
    }                                                                               \
  }

  float rs[4] = {0.f, 0.f, 0.f, 0.f};
  STAGE_K1(tk0, 0);
  __syncthreads();
  int cur = 0;
  for (int tk = 0; tk < 16; ++tk) {
    if (tk + 1 < 16) STAGE_K1(tk0 + tk + 1, cur ^ 1);
#pragma unroll
    for (int ct = 0; ct < 4; ++ct) {
      int row = ct * 16 + l15;
      bf16x8 kb0 = *(const bf16x8*)((const char*)Klds[cur] + row * 128 + (((lg << 4)) ^ ((row & 7) << 4)));
      bf16x8 kb1 = *(const bf16x8*)((const char*)Klds[cur] + row * 128 + ((((4 + lg) << 4)) ^ ((row & 7) << 4)));
      f32x4 a[4];
#pragma unroll
      for (int g = 0; g < 4; ++g) {
        a[g] = mfma16(kb0, qa[g][0], (f32x4){0.f, 0.f, 0.f, 0.f});
        a[g] = mfma16(kb1, qa[g][1], a[g]);
      }
#pragma unroll
      for (int g = 0; g < 4; ++g)
#pragma unroll
        for (int r = 0; r < 4; ++r) rs[g] += exp2_fast(a[g][r]);
    }
    __syncthreads();
    cur ^= 1;
  }
#undef STAGE_K1
#pragma unroll
  for (int g = 0; g < 4; ++g) {
    rs[g] += __shfl_xor(rs[g], 16, 64);
    rs[g] += __shfl_xor(rs[g], 32, 64);
  }
  if (lg == 0) {
#pragma unroll
    for (int g = 0; g < 4; ++g)
      rsbuf[(((size_t)quarter * NH + h) << 12) + w0 + g * 16 + l15] = rs[g];
  }
}

// ---------------- fused attention pass 2: 4 q-groups/wave, half k-range ----------------
// grid 512: xcd=bid&7, idx=bid>>3 (0..63); h=xcd*2+(idx>>5); rem=idx&31;
// q0=(rem>>1)*256; half=rem&1 -> k tiles [half*32, half*32+32). 2 blocks/CU.
// SWAPPED QK^T; P in registers; K/V dbuf stage-ahead; att written directly
// (disjoint k-halves); PV partials -> pctx[half] (f32), combined later.
__launch_bounds__(256, 2)
__global__ void attn_kernel(const ushort_t* __restrict__ qh, const ushort_t* __restrict__ kh,
                            const ushort_t* __restrict__ vt, const float* __restrict__ rsbuf,
                            float* __restrict__ att, float* __restrict__ pctx) {
  __shared__ __align__(16) ushort_t Klds[2][KVB * 64];  // [k-row][d] 128B rows, 8KB each
  __shared__ __align__(16) ushort_t Vlds[2][KVB * 64];  // [x][k]    128B rows, 8KB each
  const int t = threadIdx.x, wave = t >> 6, lane = t & 63;
  const int l15 = lane & 15, lg = lane >> 4;
  const int bid = blockIdx.x;
  const int xcd = bid & 7, idx = bid >> 3;       // idx 0..63
  const int h = xcd * 2 + (idx >> 5);            // 2 heads per XCD
  const int rem = idx & 31;
  const int q0 = (rem >> 1) * 256;
  const int half = rem & 1;
  const int w0 = q0 + wave * 64;                 // wave owns rows [w0, w0+64)

  bf16x8 qa[4][2];
#pragma unroll
  for (int g = 0; g < 4; ++g) {
    const ushort_t* qp = qh + (size_t)(w0 + g * 16 + l15) * DIN + h * HD + lg * 8;
    qa[g][0] = *(const bf16x8*)(qp);
    qa[g][1] = *(const bf16x8*)(qp + 32);
  }

  float lrs[4];
#pragma unroll
  for (int g = 0; g < 4; ++g) {
    size_t row = (size_t)w0 + g * 16 + l15;
    float ps = rsbuf[((size_t)(0 * NH + h) << 12) + row] + rsbuf[((size_t)(1 * NH + h) << 12) + row] +
               rsbuf[((size_t)(2 * NH + h) << 12) + row] + rsbuf[((size_t)(3 * NH + h) << 12) + row];
    lrs[g] = log2_fast(ps);
  }

  const int srow8 = lane >> 3;
  const int sslot = (lane & 7);
  const int tk0 = half * 32;

#define STAGE_K(tile, buf)                                                          \
  {                                                                                 \
    _Pragma("unroll") for (int c = 0; c < 2; ++c) {                                 \
      int chunk = wave * 2 + c;                                                     \
      int row = chunk * 8 + srow8;                                                  \
      int ss = sslot ^ (row & 7);                                                   \
      gld_lds16(kh + (size_t)((tile) * KVB + row) * DIN + h * HD + ss * 8,          \
                (char*)Klds[buf] + chunk * 1024);                                   \
    }                                                                               \
  }
#define STAGE_V(tile, buf)                                                          \
  {                                                                                 \
    _Pragma("unroll") for (int c = 0; c < 2; ++c) {                                 \
      int chunk = wave * 2 + c;                                                     \
      int row = chunk * 8 + srow8;                                                  \
      int ss = sslot ^ (row & 7);                                                   \
      gld_lds16(vt + ((size_t)h * HD + row) * (size_t)LKS + (tile) * KVB + ss * 8,  \
                (char*)Vlds[buf] + chunk * 1024);                                   \
    }                                                                               \
  }

  f32x4 cacc[4][4];
#pragma unroll
  for (int g = 0; g < 4; ++g)
#pragma unroll
    for (int x = 0; x < 4; ++x) cacc[g][x] = (f32x4){0.f, 0.f, 0.f, 0.f};
  float* atth = att + ((size_t)h << 24);

  STAGE_K(tk0, 0);
  STAGE_V(tk0, 0);
  __syncthreads();
  int cur = 0;
  for (int tk = 0; tk < 32; ++tk) {
    if (tk + 1 < 32) {
      STAGE_K(tk0 + tk + 1, cur ^ 1);
      STAGE_V(tk0 + tk + 1, cur ^ 1);
    }
    // QK^T (swapped) -> p per (group, ct); pack incrementally into pa
    bf16x8 pa[4][2];
    float pprev[4][4];
#pragma unroll
    for (int ct = 0; ct < 4; ++ct) {
      int row = ct * 16 + l15;
      bf16x8 kb0 = *(const bf16x8*)((const char*)Klds[cur] + row * 128 + (((lg << 4)) ^ ((row & 7) << 4)));
      bf16x8 kb1 = *(const bf16x8*)((const char*)Klds[cur] + row * 128 + ((((4 + lg) << 4)) ^ ((row & 7) << 4)));
      f32x4 a[4];
#pragma unroll
      for (int g = 0; g < 4; ++g) {
        a[g] = mfma16(kb0, qa[g][0], (f32x4){0.f, 0.f, 0.f, 0.f});
        a[g] = mfma16(kb1, qa[g][1], a[g]);
      }
      float pcur[4][4];
#pragma unroll
      for (int g = 0; g < 4; ++g)
#pragma unroll
        for (int r = 0; r < 4; ++r) pcur[g][r] = exp2_fast(a[g][r] - lrs[g]);
      // att store: one dwordx4 per (g): 16 rows x 64B per instr across the wave
#pragma unroll
      for (int g = 0; g < 4; ++g) {
        f32x4 v = (f32x4){pcur[g][0], pcur[g][1], pcur[g][2], pcur[g][3]};
        *(f32x4*)(atth + (((size_t)(w0 + g * 16 + l15)) << 12) + (tk0 + tk) * KVB + ct * 16 + lg * 4) = v;
      }
      if (ct & 1) {
#pragma unroll
        for (int g = 0; g < 4; ++g) {
          union { unsigned w[4]; bf16x8 v; } P;
          P.w[0] = cvt_pk_bf16(pprev[g][0], pprev[g][1]);
          P.w[1] = cvt_pk_bf16(pprev[g][2], pprev[g][3]);
          P.w[2] = cvt_pk_bf16(pcur[g][0], pcur[g][1]);
          P.w[3] = cvt_pk_bf16(pcur[g][2], pcur[g][3]);
          pa[g][ct >> 1] = P.v;
        }
      } else {
#pragma unroll
        for (int g = 0; g < 4; ++g)
#pragma unroll
          for (int r = 0; r < 4; ++r) pprev[g][r] = pcur[g][r];
      }
    }
    // PV: V reads shared by all 4 groups (sigma folded into addressing)
#pragma unroll
    for (int x = 0; x < 4; ++x) {
      int row = x * 16 + l15;
      const char* vrow = (const char*)Vlds[cur] + row * 128;
      int par = row & 7;
      int sb = (lg & 1) << 3;
#pragma unroll
      for (int kk = 0; kk < 2; ++kk) {
        int sA = (4 * kk + (lg >> 1)) ^ par;
        int sB = (4 * kk + 2 + (lg >> 1)) ^ par;
        union { unsigned long long q[2]; bf16x8 v; } U;
        U.q[0] = *(const unsigned long long*)(vrow + (sA << 4) + sb);
        U.q[1] = *(const unsigned long long*)(vrow + (sB << 4) + sb);
#pragma unroll
        for (int g = 0; g < 4; ++g) cacc[g][x] = mfma16(pa[g][kk], U.v, cacc[g][x]);
      }
    }
    __syncthreads();
    cur ^= 1;
  }
#undef STAGE_K
#undef STAGE_V
  // PV partials -> pctx[half]; D[row=q(lg*4+r)][col=x(l15)] per group
  float* pc = pctx + (size_t)half * LQS * DIN;
#pragma unroll
  for (int g = 0; g < 4; ++g)
#pragma unroll
    for (int x = 0; x < 4; ++x) {
#pragma unroll
      for (int r = 0; r < 4; ++r) {
        int rowq = w0 + g * 16 + lg * 4 + r;
        int col = h * HD + x * 16 + l15;
        pc[(size_t)rowq * DIN + col] = cacc[g][x][r];
      }
    }
}

extern "C" void kernel_launch(void* const* d_in, const int* in_sizes, int n_in,
                              void* d_out, int out_size, void* d_ws, size_t ws_size,
                              hipStream_t stream) {
  const float* q = (const float*)d_in[0];
  const float* k = (const float*)d_in[1];
  const float* v = (const float*)d_in[2];
  const float* Wq = (const float*)d_in[3];
  const float* bq = (const float*)d_in[4];
  const float* Wk = (const float*)d_in[5];
  const float* bk = (const float*)d_in[6];
  const float* Wv = (const float*)d_in[7];
  const float* bv = (const float*)d_in[8];
  const float* Wo = (const float*)d_in[9];
  const float* bo = (const float*)d_in[10];

  float* out = (float*)d_out;
  float* att = out + (size_t)LQS * DIN;

  char* ws = (char*)d_ws;
  ushort_t* qhb = (ushort_t*)(ws + (size_t)0);
  ushort_t* khb = (ushort_t*)(ws + ((size_t)8 << 20));
  ushort_t* vhb = (ushort_t*)(ws + ((size_t)16 << 20));
  ushort_t* vtb = (ushort_t*)(ws + ((size_t)24 << 20));
  ushort_t* ctx = (ushort_t*)(ws + ((size_t)32 << 20));
  ushort_t* qb = (ushort_t*)(ws + ((size_t)40 << 20));
  ushort_t* kb = (ushort_t*)(ws + ((size_t)48 << 20));
  ushort_t* vb = (ushort_t*)(ws + ((size_t)56 << 20));
  ushort_t* Wqt = (ushort_t*)(ws + ((size_t)64 << 20));
  ushort_t* Wkt = (ushort_t*)(ws + ((size_t)66 << 20));
  ushort_t* Wvt = (ushort_t*)(ws + ((size_t)68 << 20));
  float* pctx = (float*)(ws + ((size_t)40 << 20));   // 32MB, overlays qb/kb/vb/Wqt/Wkt/Wvt (dead by attn)
  ushort_t* Wot = (ushort_t*)(ws + ((size_t)72 << 20));
  float* rsbuf = (float*)(ws + ((size_t)74 << 20));  // [4][16][4096] f32 = 1MB

  Cvt3 c3;
  c3.src[0] = q; c3.src[1] = k; c3.src[2] = v;
  c3.dst[0] = qb; c3.dst[1] = kb; c3.dst[2] = vb;
  cvt_kernel<<<dim3(LQS * DIN / 8 / 256, 3), 256, 0, stream>>>(c3);

  TW4 w4;
  w4.W[0] = Wq; w4.W[1] = Wk; w4.W[2] = Wv; w4.W[3] = Wo;
  w4.Wt[0] = Wqt; w4.Wt[1] = Wkt; w4.Wt[2] = Wvt; w4.Wt[3] = Wot;
  transpose_w<<<dim3(16, 16, 4), 256, 0, stream>>>(w4);

  Batch3 pb;
  pb.A[0] = qb; pb.A[1] = kb; pb.A[2] = vb;
  pb.Bt[0] = Wqt; pb.Bt[1] = Wkt; pb.Bt[2] = Wvt;
  pb.bias[0] = bq; pb.bias[1] = bk; pb.bias[2] = bv;
  pb.C[0] = qhb; pb.C[1] = khb; pb.C[2] = vhb;
  pb.scale[0] = TAU_S * LOG2E; pb.scale[1] = 1.0f; pb.scale[2] = 1.0f;
  gemm_nt<false><<<768, 256, 0, stream>>>(pb);

  rowsum_kernel<<<1024, 256, 0, stream>>>(qhb, khb, rsbuf);

  transpose_v<<<dim3(64, 16), 256, 0, stream>>>(vhb, vtb);

  attn_kernel<<<512, 256, 0, stream>>>(qhb, khb, vtb, rsbuf, att, pctx);

  combine_ctx<<<LQS * DIN / 8 / 256, 256, 0, stream>>>(pctx, pctx + (size_t)LQS * DIN, ctx);

  Batch3 ob;
  ob.A[0] = ctx; ob.A[1] = ctx; ob.A[2] = ctx;
  ob.Bt[0] = Wot; ob.Bt[1] = Wot; ob.Bt[2] = Wot;
  ob.bias[0] = bo; ob.bias[1] = bo; ob.bias[2] = bo;
  ob.C[0] = out; ob.C[1] = out; ob.C[2] = out;
  ob.scale[0] = 1.0f; ob.scale[1] = 1.0f; ob.scale[2] = 1.0f;
  gemm_nt<true><<<256, 256, 0, stream>>>(ob);
}

// Round 14
// 388.236 us; speedup vs baseline: 1.1157x; 1.1157x over previous
//
#include <hip/hip_runtime.h>
#include <hip/hip_bf16.h>

typedef unsigned short ushort_t;
typedef __attribute__((ext_vector_type(8))) short short8;
typedef __attribute__((ext_vector_type(8))) __bf16 bf16x8;
typedef __attribute__((ext_vector_type(4))) float f32x4;

#define LQS 4096
#define LKS 4096
#define NH 16
#define HD 64
#define DIN 1024
#define KVB 64
static constexpr float TAU_S = 0.125f;  // 1/sqrt(64)
static constexpr float LOG2E = 1.4426950408889634f;

__device__ __forceinline__ float exp2_fast(float x) { return __builtin_amdgcn_exp2f(x); }
__device__ __forceinline__ float log2_fast(float x) { return __builtin_amdgcn_logf(x); }

__device__ __forceinline__ ushort_t f32_to_bf16(float x) {
  union { float f; unsigned u; } v; v.f = x;
  unsigned r = v.u + 0x7FFF + ((v.u >> 16) & 1);
  return (ushort_t)(r >> 16);
}

__device__ __forceinline__ unsigned cvt_pk_bf16(float a, float b) {
  unsigned r;
  asm volatile("v_cvt_pk_bf16_f32 %0, %1, %2" : "=v"(r) : "v"(a), "v"(b));
  return r;
}

__device__ __forceinline__ void gld_lds16(const void* g, void* l) {
  __builtin_amdgcn_global_load_lds((const __attribute__((address_space(1))) void*)g,
                                   (__attribute__((address_space(3))) void*)l, 16, 0, 0);
}

__device__ __forceinline__ f32x4 mfma16(bf16x8 a, bf16x8 b, f32x4 c) {
  return __builtin_amdgcn_mfma_f32_16x16x32_bf16(a, b, c, 0, 0, 0);
}

// ---------------- batched convert f32 -> bf16 (8 elems/thread) ----------------
struct Cvt3 { const float* src[3]; ushort_t* dst[3]; };
__global__ void cvt_kernel(Cvt3 c) {
  const float* __restrict__ src = c.src[blockIdx.y];
  ushort_t* __restrict__ dst = c.dst[blockIdx.y];
  int i = (blockIdx.x * 256 + threadIdx.x) * 8;
  float4 a = *(const float4*)(src + i);
  float4 b = *(const float4*)(src + i + 4);
  union { unsigned w[4]; short8 s; } o;
  o.w[0] = cvt_pk_bf16(a.x, a.y);
  o.w[1] = cvt_pk_bf16(a.z, a.w);
  o.w[2] = cvt_pk_bf16(b.x, b.y);
  o.w[3] = cvt_pk_bf16(b.z, b.w);
  *(short8*)(dst + i) = o.s;
}

// ---------------- combine PV partial sums -> ctx bf16 ----------------
__global__ void combine_ctx(const float* __restrict__ p0, const float* __restrict__ p1,
                            ushort_t* __restrict__ ctx) {
  int i = (blockIdx.x * 256 + threadIdx.x) * 8;
  float4 a0 = *(const float4*)(p0 + i);
  float4 b0 = *(const float4*)(p0 + i + 4);
  float4 a1 = *(const float4*)(p1 + i);
  float4 b1 = *(const float4*)(p1 + i + 4);
  union { unsigned w[4]; short8 s; } o;
  o.w[0] = cvt_pk_bf16(a0.x + a1.x, a0.y + a1.y);
  o.w[1] = cvt_pk_bf16(a0.z + a1.z, a0.w + a1.w);
  o.w[2] = cvt_pk_bf16(b0.x + b1.x, b0.y + b1.y);
  o.w[3] = cvt_pk_bf16(b0.z + b1.z, b0.w + b1.w);
  *(short8*)(ctx + i) = o.s;
}

// ---------------- batched transpose + convert W [1024][1024] f32 -> bf16 ----------------
struct TW4 { const float* W[4]; ushort_t* Wt[4]; };
__global__ void transpose_w(TW4 w) {
  const float* __restrict__ W = w.W[blockIdx.z];
  ushort_t* __restrict__ Wt = w.Wt[blockIdx.z];
  __shared__ float tile[64][65];
  const int t = threadIdx.x;
  const int k0 = blockIdx.y * 64, n0 = blockIdx.x * 64;
#pragma unroll
  for (int i = 0; i < 16; ++i) {
    int idx = i * 256 + t;
    int r = idx >> 6, c = idx & 63;
    tile[r][c] = W[(size_t)(k0 + r) * DIN + n0 + c];
  }
  __syncthreads();
#pragma unroll
  for (int i = 0; i < 16; ++i) {
    int idx = i * 256 + t;
    int r = idx >> 6, c = idx & 63;  // r: n-local, c: k-local
    Wt[(size_t)(n0 + r) * DIN + k0 + c] = f32_to_bf16(tile[c][r]);
  }
}

// ---------------- transpose vh [4096][16*64] -> vt [16][64][4096] ----------------
__global__ void transpose_v(const ushort_t* __restrict__ vh, ushort_t* __restrict__ vt) {
  __shared__ ushort_t tile[64][65];
  const int t = threadIdx.x;
  const int k0 = blockIdx.x * 64, h = blockIdx.y;
#pragma unroll
  for (int i = 0; i < 16; ++i) {
    int idx = i * 256 + t;
    int r = idx >> 6, c = idx & 63;  // r: k-local, c: x
    tile[r][c] = vh[(size_t)(k0 + r) * DIN + h * HD + c];
  }
  __syncthreads();
#pragma unroll
  for (int i = 0; i < 16; ++i) {
    int idx = i * 256 + t;
    int r = idx >> 6, c = idx & 63;  // r: x, c: k-local
    vt[((size_t)h * HD + r) * (size_t)LKS + k0 + c] = tile[c][r];
  }
}

// ---------------- NT GEMM (128x128, BK=64, 4 waves 2x2), XCD-swizzled 1D grid --------
struct Batch3 {
  const ushort_t* A[3];
  const ushort_t* Bt[3];
  const float* bias[3];
  void* C[3];
  float scale[3];
};
template <bool OUT_F32>
__launch_bounds__(256, 2)
__global__ void gemm_nt(Batch3 bt3) {
  const int bid = blockIdx.x;
  const int xcd = bid & 7, idx = bid >> 3;
  const int z = idx >> 5, rem = idx & 31;
  const int by = xcd * 4 + (rem >> 3), bx = rem & 7;
  const ushort_t* __restrict__ A = bt3.A[z];
  const ushort_t* __restrict__ Bt = bt3.Bt[z];
  const float* __restrict__ bias = bt3.bias[z];
  void* __restrict__ Cout = bt3.C[z];
  const float scale = bt3.scale[z];
  const int K = DIN, N = DIN;

  __shared__ __align__(16) ushort_t Alds[128 * 64];
  __shared__ __align__(16) ushort_t Blds[128 * 64];
  const int t = threadIdx.x, wave = t >> 6, lane = t & 63;
  const int l15 = lane & 15, lg = lane >> 4;
  const int m0 = by * 128, n0 = bx * 128;
  const int wr = wave >> 1, wc = wave & 1;
  f32x4 acc[4][4];
#pragma unroll
  for (int i = 0; i < 4; ++i)
#pragma unroll
    for (int j = 0; j < 4; ++j) acc[i][j] = (f32x4){0.f, 0.f, 0.f, 0.f};

  for (int tk = 0; tk < K / 64; ++tk) {
#pragma unroll
    for (int c = 0; c < 4; ++c) {
      int chunk = wave * 4 + c;
      int row = chunk * 8 + (lane >> 3);
      int ss = (lane & 7) ^ (row & 7);
      gld_lds16(A + (size_t)(m0 + row) * K + tk * 64 + ss * 8, (char*)Alds + chunk * 1024);
      gld_lds16(Bt + (size_t)(n0 + row) * K + tk * 64 + ss * 8, (char*)Blds + chunk * 1024);
    }
    __syncthreads();
#pragma unroll
    for (int kk = 0; kk < 2; ++kk) {
      bf16x8 a[4], b[4];
#pragma unroll
      for (int i = 0; i < 4; ++i) {
        int ra = wr * 64 + i * 16 + l15;
        a[i] = *(const bf16x8*)((const char*)Alds + ra * 128 + ((((kk * 4 + lg) << 4)) ^ ((ra & 7) << 4)));
        int rb = wc * 64 + i * 16 + l15;
        b[i] = *(const bf16x8*)((const char*)Blds + rb * 128 + ((((kk * 4 + lg) << 4)) ^ ((rb & 7) << 4)));
      }
#pragma unroll
      for (int mi = 0; mi < 4; ++mi)
#pragma unroll
        for (int ni = 0; ni < 4; ++ni)
          acc[mi][ni] = mfma16(a[mi], b[ni], acc[mi][ni]);
    }
    __syncthreads();
  }
#pragma unroll
  for (int ni = 0; ni < 4; ++ni) {
    int coln = n0 + wc * 64 + ni * 16 + l15;
    float bv = bias[coln];
#pragma unroll
    for (int mi = 0; mi < 4; ++mi) {
#pragma unroll
      for (int r = 0; r < 4; ++r) {
        int rowm = m0 + wr * 64 + mi * 16 + lg * 4 + r;
        float v = (acc[mi][ni][r] + bv) * scale;
        if (OUT_F32)
          ((float*)Cout)[(size_t)rowm * N + coln] = v;
        else
          ((ushort_t*)Cout)[(size_t)rowm * N + coln] = f32_to_bf16(v);
      }
    }
  }
}

// ---------------- rowsum kernel: half k-range, grid 512 (R12-proven) ----------------
__launch_bounds__(256, 2)
__global__ void rowsum_kernel(const ushort_t* __restrict__ qh, const ushort_t* __restrict__ kh,
                              float* __restrict__ rsbuf) {
  __shared__ __align__(16) ushort_t Klds[2][KVB * 64];
  const int t = threadIdx.x, wave = t >> 6, lane = t & 63;
  const int l15 = lane & 15, lg = lane >> 4;
  const int bid = blockIdx.x;
  const int xcd = bid & 7, idx = bid >> 3;   // idx 0..63
  const int h = xcd * 2 + (idx >> 5);        // 2 heads per XCD
  const int rem = idx & 31;
  const int q0 = (rem >> 1) * 256;
  const int half = rem & 1;
  const int w0 = q0 + wave * 64;

  bf16x8 qa[4][2];
#pragma unroll
  for (int g = 0; g < 4; ++g) {
    const ushort_t* qp = qh + (size_t)(w0 + g * 16 + l15) * DIN + h * HD + lg * 8;
    qa[g][0] = *(const bf16x8*)(qp);
    qa[g][1] = *(const bf16x8*)(qp + 32);
  }

  const int srow8 = lane >> 3;
  const int sslot = (lane & 7);
  const int tk0 = half * 32;

#define STAGE_K1(tile, buf)                                                         \
  {                                                                                 \
    _Pragma("unroll") for (int c = 0; c < 2; ++c) {                                 \
      int chunk = wave * 2 + c;                                                     \
      int row = chunk * 8 + srow8;                                                  \
      int ss = sslot ^ (row & 7);                                                   \
      gld_lds16(kh + (size_t)((tile) * KVB + row) * DIN + h * HD + ss * 8,          \
                (char*)Klds[buf] + chunk * 1024);                                   \
    }                                                                               \
  }

  float rs[4] = {0.f, 0.f, 0.f, 0.f};
  STAGE_K1(tk0, 0);
  __syncthreads();
  int cur = 0;
  for (int tk = 0; tk < 32; ++tk) {
    if (tk + 1 < 32) STAGE_K1(tk0 + tk + 1, cur ^ 1);
#pragma unroll
    for (int ct = 0; ct < 4; ++ct) {
      int row = ct * 16 + l15;
      bf16x8 kb0 = *(const bf16x8*)((const char*)Klds[cur] + row * 128 + (((lg << 4)) ^ ((row & 7) << 4)));
      bf16x8 kb1 = *(const bf16x8*)((const char*)Klds[cur] + row * 128 + ((((4 + lg) << 4)) ^ ((row & 7) << 4)));
      f32x4 a[4];
#pragma unroll
      for (int g = 0; g < 4; ++g) {
        a[g] = mfma16(kb0, qa[g][0], (f32x4){0.f, 0.f, 0.f, 0.f});
        a[g] = mfma16(kb1, qa[g][1], a[g]);
      }
#pragma unroll
      for (int g = 0; g < 4; ++g)
#pragma unroll
        for (int r = 0; r < 4; ++r) rs[g] += exp2_fast(a[g][r]);
    }
    __syncthreads();
    cur ^= 1;
  }
#undef STAGE_K1
#pragma unroll
  for (int g = 0; g < 4; ++g) {
    rs[g] += __shfl_xor(rs[g], 16, 64);
    rs[g] += __shfl_xor(rs[g], 32, 64);
  }
  if (lg == 0) {
#pragma unroll
    for (int g = 0; g < 4; ++g)
      rsbuf[(((size_t)half * NH + h) << 12) + w0 + g * 16 + l15] = rs[g];
  }
}

// ---------------- fused attention pass 2: 2 q-groups/wave, half k, 4 blocks/CU -------
// grid 1024: xcd=bid&7, idx=bid>>3 (0..127); h=xcd*2+(idx>>6); rem=idx&63;
// q0=(rem>>1)*128; half=rem&1 -> k tiles [half*32, half*32+32).
// R12-proven round structure (2 sub-tiles per barrier round); incremental pa pack
// (low VGPR for 4 waves/SIMD); att written directly; PV partials -> pctx[half].
__launch_bounds__(256, 4)
__global__ void attn_kernel(const ushort_t* __restrict__ qh, const ushort_t* __restrict__ kh,
                            const ushort_t* __restrict__ vt, const float* __restrict__ rsbuf,
                            float* __restrict__ att, float* __restrict__ pctx) {
  __shared__ __align__(16) ushort_t Klds[2][KVB * 64];  // [k-row][d] 128B rows, 8KB each
  __shared__ __align__(16) ushort_t Vlds[2][KVB * 64];  // [x][k]    128B rows, 8KB each
  const int t = threadIdx.x, wave = t >> 6, lane = t & 63;
  const int l15 = lane & 15, lg = lane >> 4;
  const int bid = blockIdx.x;
  const int xcd = bid & 7, idx = bid >> 3;       // idx 0..127
  const int h = xcd * 2 + (idx >> 6);            // 2 heads per XCD
  const int rem = idx & 63;
  const int q0 = (rem >> 1) * 128;
  const int half = rem & 1;
  const int w0 = q0 + wave * 32;                 // wave owns rows [w0, w0+32)

  bf16x8 qa[2][2];
#pragma unroll
  for (int g = 0; g < 2; ++g) {
    const ushort_t* qp = qh + (size_t)(w0 + g * 16 + l15) * DIN + h * HD + lg * 8;
    qa[g][0] = *(const bf16x8*)(qp);
    qa[g][1] = *(const bf16x8*)(qp + 32);
  }

  float lrs[2];
#pragma unroll
  for (int g = 0; g < 2; ++g) {
    size_t row = (size_t)w0 + g * 16 + l15;
    float ps = rsbuf[((size_t)h << 12) + row] + rsbuf[(((size_t)NH + h) << 12) + row];
    lrs[g] = log2_fast(ps);
  }

  const int srow8 = lane >> 3;
  const int sslot = (lane & 7);
  const int tb0 = half * 32;                     // base tile of this k-half

  f32x4 cacc[2][4];
#pragma unroll
  for (int g = 0; g < 2; ++g)
#pragma unroll
    for (int x = 0; x < 4; ++x) cacc[g][x] = (f32x4){0.f, 0.f, 0.f, 0.f};
  float* atth = att + ((size_t)h << 24);

  for (int tk = 0; tk < 16; ++tk) {
#pragma unroll
    for (int sub = 0; sub < 2; ++sub) {
#pragma unroll
      for (int c = 0; c < 2; ++c) {
        int chunk = wave * 2 + c;
        int row = chunk * 8 + srow8;
        int ss = sslot ^ (row & 7);
        gld_lds16(kh + (size_t)((tb0 + tk * 2 + sub) * KVB + row) * DIN + h * HD + ss * 8,
                  (char*)Klds[sub] + chunk * 1024);
        gld_lds16(vt + ((size_t)h * HD + row) * (size_t)LKS + (tb0 + tk * 2 + sub) * KVB + ss * 8,
                  (char*)Vlds[sub] + chunk * 1024);
      }
    }
    __syncthreads();
#pragma unroll
    for (int sub = 0; sub < 2; ++sub) {
      // QK^T (swapped) per ct; incremental pack into pa (low VGPR)
      bf16x8 pa[2][2];
      float pprev[2][4];
#pragma unroll
      for (int ct = 0; ct < 4; ++ct) {
        f32x4 a0 = (f32x4){0.f, 0.f, 0.f, 0.f};
        f32x4 a1 = (f32x4){0.f, 0.f, 0.f, 0.f};
#pragma unroll
        for (int kk = 0; kk < 2; ++kk) {
          int row = ct * 16 + l15;
          bf16x8 kb = *(const bf16x8*)((const char*)Klds[sub] + row * 128 + ((((kk * 4 + lg) << 4)) ^ ((row & 7) << 4)));
          a0 = mfma16(kb, qa[0][kk], a0);
          a1 = mfma16(kb, qa[1][kk], a1);
        }
        float pcur[2][4];
#pragma unroll
        for (int r = 0; r < 4; ++r) {
          pcur[0][r] = exp2_fast(a0[r] - lrs[0]);
          pcur[1][r] = exp2_fast(a1[r] - lrs[1]);
        }
        // att store: one dwordx4 per group (16 rows x 64B per instr across the wave)
#pragma unroll
        for (int g = 0; g < 2; ++g) {
          f32x4 v = (f32x4){pcur[g][0], pcur[g][1], pcur[g][2], pcur[g][3]};
          *(f32x4*)(atth + (((size_t)(w0 + g * 16 + l15)) << 12) + (tb0 + tk * 2 + sub) * KVB + ct * 16 + lg * 4) = v;
        }
        if (ct & 1) {
#pragma unroll
          for (int g = 0; g < 2; ++g) {
            union { unsigned w[4]; bf16x8 v; } P;
            P.w[0] = cvt_pk_bf16(pprev[g][0], pprev[g][1]);
            P.w[1] = cvt_pk_bf16(pprev[g][2], pprev[g][3]);
            P.w[2] = cvt_pk_bf16(pcur[g][0], pcur[g][1]);
            P.w[3] = cvt_pk_bf16(pcur[g][2], pcur[g][3]);
            pa[g][ct >> 1] = P.v;
          }
        } else {
#pragma unroll
          for (int g = 0; g < 2; ++g)
#pragma unroll
            for (int r = 0; r < 4; ++r) pprev[g][r] = pcur[g][r];
        }
      }
      // PV: V reads shared across groups (sigma folded into addressing)
#pragma unroll
      for (int x = 0; x < 4; ++x) {
        int row = x * 16 + l15;
        const char* vrow = (const char*)Vlds[sub] + row * 128;
        int par = row & 7;
        int sb = (lg & 1) << 3;
#pragma unroll
        for (int kk = 0; kk < 2; ++kk) {
          int sA = (4 * kk + (lg >> 1)) ^ par;
          int sB = (4 * kk + 2 + (lg >> 1)) ^ par;
          union { unsigned long long q[2]; bf16x8 v; } U;
          U.q[0] = *(const unsigned long long*)(vrow + (sA << 4) + sb);
          U.q[1] = *(const unsigned long long*)(vrow + (sB << 4) + sb);
          cacc[0][x] = mfma16(pa[0][kk], U.v, cacc[0][x]);
          cacc[1][x] = mfma16(pa[1][kk], U.v, cacc[1][x]);
        }
      }
    }
    __syncthreads();
  }
  // PV partials -> pctx[half]; D[row=q(lg*4+r)][col=x(l15)] per group
  float* pc = pctx + (size_t)half * LQS * DIN;
#pragma unroll
  for (int g = 0; g < 2; ++g)
#pragma unroll
    for (int x = 0; x < 4; ++x) {
#pragma unroll
      for (int r = 0; r < 4; ++r) {
        int rowq = w0 + g * 16 + lg * 4 + r;
        int col = h * HD + x * 16 + l15;
        pc[(size_t)rowq * DIN + col] = cacc[g][x][r];
      }
    }
}

extern "C" void kernel_launch(void* const* d_in, const int* in_sizes, int n_in,
                              void* d_out, int out_size, void* d_ws, size_t ws_size,
                              hipStream_t stream) {
  const float* q = (const float*)d_in[0];
  const float* k = (const float*)d_in[1];
  const float* v = (const float*)d_in[2];
  const float* Wq = (const float*)d_in[3];
  const float* bq = (const float*)d_in[4];
  const float* Wk = (const float*)d_in[5];
  const float* bk = (const float*)d_in[6];
  const float* Wv = (const float*)d_in[7];
  const float* bv = (const float*)d_in[8];
  const float* Wo = (const float*)d_in[9];
  const float* bo = (const float*)d_in[10];

  float* out = (float*)d_out;
  float* att = out + (size_t)LQS * DIN;

  char* ws = (char*)d_ws;
  ushort_t* qhb = (ushort_t*)(ws + (size_t)0);
  ushort_t* khb = (ushort_t*)(ws + ((size_t)8 << 20));
  ushort_t* vhb = (ushort_t*)(ws + ((size_t)16 << 20));
  ushort_t* vtb = (ushort_t*)(ws + ((size_t)24 << 20));
  ushort_t* ctx = (ushort_t*)(ws + ((size_t)32 << 20));
  ushort_t* qb = (ushort_t*)(ws + ((size_t)40 << 20));
  ushort_t* kb = (ushort_t*)(ws + ((size_t)48 << 20));
  ushort_t* vb = (ushort_t*)(ws + ((size_t)56 << 20));
  ushort_t* Wqt = (ushort_t*)(ws + ((size_t)64 << 20));
  ushort_t* Wkt = (ushort_t*)(ws + ((size_t)66 << 20));
  ushort_t* Wvt = (ushort_t*)(ws + ((size_t)68 << 20));
  float* pctx = (float*)(ws + ((size_t)40 << 20));   // 32MB, overlays qb/kb/vb/Wqt/Wkt/Wvt (dead by attn)
  ushort_t* Wot = (ushort_t*)(ws + ((size_t)72 << 20));
  float* rsbuf = (float*)(ws + ((size_t)74 << 20));  // [2][16][4096] f32 = 512KB

  Cvt3 c3;
  c3.src[0] = q; c3.src[1] = k; c3.src[2] = v;
  c3.dst[0] = qb; c3.dst[1] = kb; c3.dst[2] = vb;
  cvt_kernel<<<dim3(LQS * DIN / 8 / 256, 3), 256, 0, stream>>>(c3);

  TW4 w4;
  w4.W[0] = Wq; w4.W[1] = Wk; w4.W[2] = Wv; w4.W[3] = Wo;
  w4.Wt[0] = Wqt; w4.Wt[1] = Wkt; w4.Wt[2] = Wvt; w4.Wt[3] = Wot;
  transpose_w<<<dim3(16, 16, 4), 256, 0, stream>>>(w4);

  Batch3 pb;
  pb.A[0] = qb; pb.A[1] = kb; pb.A[2] = vb;
  pb.Bt[0] = Wqt; pb.Bt[1] = Wkt; pb.Bt[2] = Wvt;
  pb.bias[0] = bq; pb.bias[1] = bk; pb.bias[2] = bv;
  pb.C[0] = qhb; pb.C[1] = khb; pb.C[2] = vhb;
  pb.scale[0] = TAU_S * LOG2E; pb.scale[1] = 1.0f; pb.scale[2] = 1.0f;
  gemm_nt<false><<<768, 256, 0, stream>>>(pb);

  rowsum_kernel<<<512, 256, 0, stream>>>(qhb, khb, rsbuf);

  transpose_v<<<dim3(64, 16), 256, 0, stream>>>(vhb, vtb);

  attn_kernel<<<1024, 256, 0, stream>>>(qhb, khb, vtb, rsbuf, att, pctx);

  combine_ctx<<<LQS * DIN / 8 / 256, 256, 0, stream>>>(pctx, pctx + (size_t)LQS * DIN, ctx);

  Batch3 ob;
  ob.A[0] = ctx; ob.A[1] = ctx; ob.A[2] = ctx;
  ob.Bt[0] = Wot; ob.Bt[1] = Wot; ob.Bt[2] = Wot;
  ob.bias[0] = bo; ob.bias[1] = bo; ob.bias[2] = bo;
  ob.C[0] = out; ob.C[1] = out; ob.C[2] = out;
  ob.scale[0] = 1.0f; ob.scale[1] = 1.0f; ob.scale[2] = 1.0f;
  gemm_nt<true><<<256, 256, 0, stream>>>(ob);
}

// Round 15
// 381.347 us; speedup vs baseline: 1.1359x; 1.0181x over previous
//
#include <hip/hip_runtime.h>
#include <hip/hip_bf16.h>

typedef unsigned short ushort_t;
typedef __attribute__((ext_vector_type(8))) short short8;
typedef __attribute__((ext_vector_type(8))) __bf16 bf16x8;
typedef __attribute__((ext_vector_type(4))) float f32x4;

#define LQS 4096
#define LKS 4096
#define NH 16
#define HD 64
#define DIN 1024
#define KVB 64
static constexpr float TAU_S = 0.125f;  // 1/sqrt(64)
static constexpr float LOG2E = 1.4426950408889634f;

__device__ __forceinline__ float exp2_fast(float x) { return __builtin_amdgcn_exp2f(x); }
__device__ __forceinline__ float log2_fast(float x) { return __builtin_amdgcn_logf(x); }

__device__ __forceinline__ ushort_t f32_to_bf16(float x) {
  union { float f; unsigned u; } v; v.f = x;
  unsigned r = v.u + 0x7FFF + ((v.u >> 16) & 1);
  return (ushort_t)(r >> 16);
}

__device__ __forceinline__ unsigned cvt_pk_bf16(float a, float b) {
  unsigned r;
  asm volatile("v_cvt_pk_bf16_f32 %0, %1, %2" : "=v"(r) : "v"(a), "v"(b));
  return r;
}

__device__ __forceinline__ void gld_lds16(const void* g, void* l) {
  __builtin_amdgcn_global_load_lds((const __attribute__((address_space(1))) void*)g,
                                   (__attribute__((address_space(3))) void*)l, 16, 0, 0);
}

__device__ __forceinline__ f32x4 mfma16(bf16x8 a, bf16x8 b, f32x4 c) {
  return __builtin_amdgcn_mfma_f32_16x16x32_bf16(a, b, c, 0, 0, 0);
}

// ---------------- batched convert f32 -> bf16 (8 elems/thread) ----------------
struct Cvt3 { const float* src[3]; ushort_t* dst[3]; };
__global__ void cvt_kernel(Cvt3 c) {
  const float* __restrict__ src = c.src[blockIdx.y];
  ushort_t* __restrict__ dst = c.dst[blockIdx.y];
  int i = (blockIdx.x * 256 + threadIdx.x) * 8;
  float4 a = *(const float4*)(src + i);
  float4 b = *(const float4*)(src + i + 4);
  union { unsigned w[4]; short8 s; } o;
  o.w[0] = cvt_pk_bf16(a.x, a.y);
  o.w[1] = cvt_pk_bf16(a.z, a.w);
  o.w[2] = cvt_pk_bf16(b.x, b.y);
  o.w[3] = cvt_pk_bf16(b.z, b.w);
  *(short8*)(dst + i) = o.s;
}

// ---------------- batched transpose + convert W [1024][1024] f32 -> bf16 ----------------
struct TW4 { const float* W[4]; ushort_t* Wt[4]; };
__global__ void transpose_w(TW4 w) {
  const float* __restrict__ W = w.W[blockIdx.z];
  ushort_t* __restrict__ Wt = w.Wt[blockIdx.z];
  __shared__ float tile[64][65];
  const int t = threadIdx.x;
  const int k0 = blockIdx.y * 64, n0 = blockIdx.x * 64;
#pragma unroll
  for (int i = 0; i < 16; ++i) {
    int idx = i * 256 + t;
    int r = idx >> 6, c = idx & 63;
    tile[r][c] = W[(size_t)(k0 + r) * DIN + n0 + c];
  }
  __syncthreads();
#pragma unroll
  for (int i = 0; i < 16; ++i) {
    int idx = i * 256 + t;
    int r = idx >> 6, c = idx & 63;  // r: n-local, c: k-local
    Wt[(size_t)(n0 + r) * DIN + k0 + c] = f32_to_bf16(tile[c][r]);
  }
}

// ---------------- transpose vh [4096][16*64] -> vt [16][64][4096] ----------------
__global__ void transpose_v(const ushort_t* __restrict__ vh, ushort_t* __restrict__ vt) {
  __shared__ ushort_t tile[64][65];
  const int t = threadIdx.x;
  const int k0 = blockIdx.x * 64, h = blockIdx.y;
#pragma unroll
  for (int i = 0; i < 16; ++i) {
    int idx = i * 256 + t;
    int r = idx >> 6, c = idx & 63;  // r: k-local, c: x
    tile[r][c] = vh[(size_t)(k0 + r) * DIN + h * HD + c];
  }
  __syncthreads();
#pragma unroll
  for (int i = 0; i < 16; ++i) {
    int idx = i * 256 + t;
    int r = idx >> 6, c = idx & 63;  // r: x, c: k-local
    vt[((size_t)h * HD + r) * (size_t)LKS + k0 + c] = tile[c][r];
  }
}

// ---------------- NT GEMM (128x128, BK=64, 4 waves 2x2), XCD-swizzled 1D grid --------
struct Batch3 {
  const ushort_t* A[3];
  const ushort_t* Bt[3];
  const float* bias[3];
  void* C[3];
  float scale[3];
};
template <bool OUT_F32>
__launch_bounds__(256, 2)
__global__ void gemm_nt(Batch3 bt3) {
  const int bid = blockIdx.x;
  const int xcd = bid & 7, idx = bid >> 3;
  const int z = idx >> 5, rem = idx & 31;
  const int by = xcd * 4 + (rem >> 3), bx = rem & 7;
  const ushort_t* __restrict__ A = bt3.A[z];
  const ushort_t* __restrict__ Bt = bt3.Bt[z];
  const float* __restrict__ bias = bt3.bias[z];
  void* __restrict__ Cout = bt3.C[z];
  const float scale = bt3.scale[z];
  const int K = DIN, N = DIN;

  __shared__ __align__(16) ushort_t Alds[128 * 64];
  __shared__ __align__(16) ushort_t Blds[128 * 64];
  const int t = threadIdx.x, wave = t >> 6, lane = t & 63;
  const int l15 = lane & 15, lg = lane >> 4;
  const int m0 = by * 128, n0 = bx * 128;
  const int wr = wave >> 1, wc = wave & 1;
  f32x4 acc[4][4];
#pragma unroll
  for (int i = 0; i < 4; ++i)
#pragma unroll
    for (int j = 0; j < 4; ++j) acc[i][j] = (f32x4){0.f, 0.f, 0.f, 0.f};

  for (int tk = 0; tk < K / 64; ++tk) {
#pragma unroll
    for (int c = 0; c < 4; ++c) {
      int chunk = wave * 4 + c;
      int row = chunk * 8 + (lane >> 3);
      int ss = (lane & 7) ^ (row & 7);
      gld_lds16(A + (size_t)(m0 + row) * K + tk * 64 + ss * 8, (char*)Alds + chunk * 1024);
      gld_lds16(Bt + (size_t)(n0 + row) * K + tk * 64 + ss * 8, (char*)Blds + chunk * 1024);
    }
    __syncthreads();
#pragma unroll
    for (int kk = 0; kk < 2; ++kk) {
      bf16x8 a[4], b[4];
#pragma unroll
      for (int i = 0; i < 4; ++i) {
        int ra = wr * 64 + i * 16 + l15;
        a[i] = *(const bf16x8*)((const char*)Alds + ra * 128 + ((((kk * 4 + lg) << 4)) ^ ((ra & 7) << 4)));
        int rb = wc * 64 + i * 16 + l15;
        b[i] = *(const bf16x8*)((const char*)Blds + rb * 128 + ((((kk * 4 + lg) << 4)) ^ ((rb & 7) << 4)));
      }
#pragma unroll
      for (int mi = 0; mi < 4; ++mi)
#pragma unroll
        for (int ni = 0; ni < 4; ++ni)
          acc[mi][ni] = mfma16(a[mi], b[ni], acc[mi][ni]);
    }
    __syncthreads();
  }
#pragma unroll
  for (int ni = 0; ni < 4; ++ni) {
    int coln = n0 + wc * 64 + ni * 16 + l15;
    float bv = bias[coln];
#pragma unroll
    for (int mi = 0; mi < 4; ++mi) {
#pragma unroll
      for (int r = 0; r < 4; ++r) {
        int rowm = m0 + wr * 64 + mi * 16 + lg * 4 + r;
        float v = (acc[mi][ni][r] + bv) * scale;
        if (OUT_F32)
          ((float*)Cout)[(size_t)rowm * N + coln] = v;
        else
          ((ushort_t*)Cout)[(size_t)rowm * N + coln] = f32_to_bf16(v);
      }
    }
  }
}

// ---------------- rowsum kernel: quarter k-range, 4 blocks/CU ----------------
// grid 1024: xcd=bid&7, idx=bid>>3 (0..127); h=xcd*2+(idx>>6); rem=idx&63;
// q0=(rem>>2)*256; quarter=rem&3 -> k tiles [quarter*16, quarter*16+16).
// Wave owns 64 q-rows (4 groups). f32x4 accumulators (4x ILP on add chain).
__launch_bounds__(256, 4)
__global__ void rowsum_kernel(const ushort_t* __restrict__ qh, const ushort_t* __restrict__ kh,
                              float* __restrict__ rsbuf) {
  __shared__ __align__(16) ushort_t Klds[2][KVB * 64];
  const int t = threadIdx.x, wave = t >> 6, lane = t & 63;
  const int l15 = lane & 15, lg = lane >> 4;
  const int bid = blockIdx.x;
  const int xcd = bid & 7, idx = bid >> 3;   // idx 0..127
  const int h = xcd * 2 + (idx >> 6);        // 2 heads per XCD
  const int rem = idx & 63;
  const int q0 = (rem >> 2) * 256;
  const int quarter = rem & 3;
  const int w0 = q0 + wave * 64;

  bf16x8 qa[4][2];
#pragma unroll
  for (int g = 0; g < 4; ++g) {
    const ushort_t* qp = qh + (size_t)(w0 + g * 16 + l15) * DIN + h * HD + lg * 8;
    qa[g][0] = *(const bf16x8*)(qp);
    qa[g][1] = *(const bf16x8*)(qp + 32);
  }

  const int srow8 = lane >> 3;
  const int sslot = (lane & 7);
  const int tk0 = quarter * 16;

#define STAGE_K1(tile, buf)                                                         \
  {                                                                                 \
    _Pragma("unroll") for (int c = 0; c < 2; ++c) {                                 \
      int chunk = wave * 2 + c;                                                     \
      int row = chunk * 8 + srow8;                                                  \
      int ss = sslot ^ (row & 7);                                                   \
      gld_lds16(kh + (size_t)((tile) * KVB + row) * DIN + h * HD + ss * 8,          \
                (char*)Klds[buf] + chunk * 1024);                                   \
    }                                                                               \
  }

  f32x4 rsv[4];
#pragma unroll
  for (int g = 0; g < 4; ++g) rsv[g] = (f32x4){0.f, 0.f, 0.f, 0.f};
  STAGE_K1(tk0, 0);
  __syncthreads();
  int cur = 0;
  for (int tk = 0; tk < 16; ++tk) {
    if (tk + 1 < 16) STAGE_K1(tk0 + tk + 1, cur ^ 1);
#pragma unroll
    for (int ct = 0; ct < 4; ++ct) {
      int row = ct * 16 + l15;
      bf16x8 kb0 = *(const bf16x8*)((const char*)Klds[cur] + row * 128 + (((lg << 4)) ^ ((row & 7) << 4)));
      bf16x8 kb1 = *(const bf16x8*)((const char*)Klds[cur] + row * 128 + ((((4 + lg) << 4)) ^ ((row & 7) << 4)));
      f32x4 a[4];
#pragma unroll
      for (int g = 0; g < 4; ++g) {
        a[g] = mfma16(kb0, qa[g][0], (f32x4){0.f, 0.f, 0.f, 0.f});
        a[g] = mfma16(kb1, qa[g][1], a[g]);
      }
#pragma unroll
      for (int g = 0; g < 4; ++g)
#pragma unroll
        for (int r = 0; r < 4; ++r) rsv[g][r] += exp2_fast(a[g][r]);
    }
    __syncthreads();
    cur ^= 1;
  }
#undef STAGE_K1
  float rs[4];
#pragma unroll
  for (int g = 0; g < 4; ++g) {
    rs[g] = (rsv[g][0] + rsv[g][1]) + (rsv[g][2] + rsv[g][3]);
    rs[g] += __shfl_xor(rs[g], 16, 64);
    rs[g] += __shfl_xor(rs[g], 32, 64);
  }
  if (lg == 0) {
#pragma unroll
    for (int g = 0; g < 4; ++g)
      rsbuf[(((size_t)quarter * NH + h) << 12) + w0 + g * 16 + l15] = rs[g];
  }
}

// ---------------- fused attention pass 2 (R12 structure, 4 sub-tiles/barrier) --------
// grid 512: xcd=bid&7, idx=bid>>3 (0..63); h=xcd*2+(idx>>5); q0=(idx&31)*128.
// Wave owns 32 q-rows (two 16-row groups). SWAPPED QK^T; P in registers; att written
// directly; ctx written directly. FOUR 64-row K/V sub-tiles per barrier round (64KB
// LDS, 2 blocks/CU) -> half the barrier-drains of R12, longer store windows.
__launch_bounds__(256, 2)
__global__ void attn_kernel(const ushort_t* __restrict__ qh, const ushort_t* __restrict__ kh,
                            const ushort_t* __restrict__ vt, const float* __restrict__ rsbuf,
                            float* __restrict__ att, ushort_t* __restrict__ ctx) {
  __shared__ __align__(16) ushort_t Klds[4][KVB * 64];  // 32KB
  __shared__ __align__(16) ushort_t Vlds[4][KVB * 64];  // 32KB
  const int t = threadIdx.x, wave = t >> 6, lane = t & 63;
  const int l15 = lane & 15, lg = lane >> 4;
  const int bid = blockIdx.x;
  const int xcd = bid & 7, idx = bid >> 3;       // idx 0..63
  const int h = xcd * 2 + (idx >> 5);            // 2 heads per XCD
  const int q0 = (idx & 31) * 128;
  const int w0 = q0 + wave * 32;                 // wave owns rows [w0, w0+32)

  bf16x8 qa[2][2];
#pragma unroll
  for (int g = 0; g < 2; ++g) {
    const ushort_t* qp = qh + (size_t)(w0 + g * 16 + l15) * DIN + h * HD + lg * 8;
    qa[g][0] = *(const bf16x8*)(qp);
    qa[g][1] = *(const bf16x8*)(qp + 32);
  }

  float lrs[2];
#pragma unroll
  for (int g = 0; g < 2; ++g) {
    size_t row = (size_t)w0 + g * 16 + l15;
    float ps = rsbuf[((size_t)(0 * NH + h) << 12) + row] + rsbuf[((size_t)(1 * NH + h) << 12) + row] +
               rsbuf[((size_t)(2 * NH + h) << 12) + row] + rsbuf[((size_t)(3 * NH + h) << 12) + row];
    lrs[g] = log2_fast(ps);
  }

  const int srow8 = lane >> 3;
  const int sslot = (lane & 7);

  f32x4 cacc[2][4];
#pragma unroll
  for (int g = 0; g < 2; ++g)
#pragma unroll
    for (int x = 0; x < 4; ++x) cacc[g][x] = (f32x4){0.f, 0.f, 0.f, 0.f};
  float* atth = att + ((size_t)h << 24);

  for (int tk = 0; tk < LKS / (4 * KVB); ++tk) {
#pragma unroll
    for (int sub = 0; sub < 4; ++sub) {
#pragma unroll
      for (int c = 0; c < 2; ++c) {
        int chunk = wave * 2 + c;
        int row = chunk * 8 + srow8;
        int ss = sslot ^ (row & 7);
        gld_lds16(kh + (size_t)((tk * 4 + sub) * KVB + row) * DIN + h * HD + ss * 8,
                  (char*)Klds[sub] + chunk * 1024);
        gld_lds16(vt + ((size_t)h * HD + row) * (size_t)LKS + (tk * 4 + sub) * KVB + ss * 8,
                  (char*)Vlds[sub] + chunk * 1024);
      }
    }
    __syncthreads();
#pragma unroll
    for (int sub = 0; sub < 4; ++sub) {
      // QK^T (swapped) for both groups; p normalized via exponent fold
      float p[2][4][4];
#pragma unroll
      for (int ct = 0; ct < 4; ++ct) {
        f32x4 a0 = (f32x4){0.f, 0.f, 0.f, 0.f};
        f32x4 a1 = (f32x4){0.f, 0.f, 0.f, 0.f};
#pragma unroll
        for (int kk = 0; kk < 2; ++kk) {
          int row = ct * 16 + l15;
          bf16x8 kb = *(const bf16x8*)((const char*)Klds[sub] + row * 128 + ((((kk * 4 + lg) << 4)) ^ ((row & 7) << 4)));
          a0 = mfma16(kb, qa[0][kk], a0);
          a1 = mfma16(kb, qa[1][kk], a1);
        }
#pragma unroll
        for (int r = 0; r < 4; ++r) {
          p[0][ct][r] = exp2_fast(a0[r] - lrs[0]);
          p[1][ct][r] = exp2_fast(a1[r] - lrs[1]);
        }
      }
      // att store: per group 4x dwordx4 per lane (16 rows x 64B per instr)
#pragma unroll
      for (int g = 0; g < 2; ++g) {
#pragma unroll
        for (int ct = 0; ct < 4; ++ct) {
          f32x4 v = (f32x4){p[g][ct][0], p[g][ct][1], p[g][ct][2], p[g][ct][3]};
          *(f32x4*)(atth + (((size_t)(w0 + g * 16 + l15)) << 12) + (tk * 4 + sub) * KVB + ct * 16 + lg * 4) = v;
        }
      }
      // PV: A-frags packed per group; V reads shared across groups
      bf16x8 pa[2][2];
#pragma unroll
      for (int g = 0; g < 2; ++g)
#pragma unroll
        for (int kk = 0; kk < 2; ++kk) {
          union { unsigned w[4]; bf16x8 v; } P;
          P.w[0] = cvt_pk_bf16(p[g][2 * kk][0], p[g][2 * kk][1]);
          P.w[1] = cvt_pk_bf16(p[g][2 * kk][2], p[g][2 * kk][3]);
          P.w[2] = cvt_pk_bf16(p[g][2 * kk + 1][0], p[g][2 * kk + 1][1]);
          P.w[3] = cvt_pk_bf16(p[g][2 * kk + 1][2], p[g][2 * kk + 1][3]);
          pa[g][kk] = P.v;
        }
#pragma unroll
      for (int x = 0; x < 4; ++x) {
        int row = x * 16 + l15;
        const char* vrow = (const char*)Vlds[sub] + row * 128;
        int par = row & 7;
        int sb = (lg & 1) << 3;
#pragma unroll
        for (int kk = 0; kk < 2; ++kk) {
          int sA = (4 * kk + (lg >> 1)) ^ par;
          int sB = (4 * kk + 2 + (lg >> 1)) ^ par;
          union { unsigned long long q[2]; bf16x8 v; } U;
          U.q[0] = *(const unsigned long long*)(vrow + (sA << 4) + sb);
          U.q[1] = *(const unsigned long long*)(vrow + (sB << 4) + sb);
          cacc[0][x] = mfma16(pa[0][kk], U.v, cacc[0][x]);
          cacc[1][x] = mfma16(pa[1][kk], U.v, cacc[1][x]);
        }
      }
    }
    __syncthreads();
  }
  // D[row=q(lg*4+r)][col=x(l15)] per group
#pragma unroll
  for (int g = 0; g < 2; ++g)
#pragma unroll
    for (int x = 0; x < 4; ++x) {
#pragma unroll
      for (int r = 0; r < 4; ++r) {
        int rowq = w0 + g * 16 + lg * 4 + r;
        int col = h * HD + x * 16 + l15;
        ctx[(size_t)rowq * DIN + col] = f32_to_bf16(cacc[g][x][r]);
      }
    }
}

extern "C" void kernel_launch(void* const* d_in, const int* in_sizes, int n_in,
                              void* d_out, int out_size, void* d_ws, size_t ws_size,
                              hipStream_t stream) {
  const float* q = (const float*)d_in[0];
  const float* k = (const float*)d_in[1];
  const float* v = (const float*)d_in[2];
  const float* Wq = (const float*)d_in[3];
  const float* bq = (const float*)d_in[4];
  const float* Wk = (const float*)d_in[5];
  const float* bk = (const float*)d_in[6];
  const float* Wv = (const float*)d_in[7];
  const float* bv = (const float*)d_in[8];
  const float* Wo = (const float*)d_in[9];
  const float* bo = (const float*)d_in[10];

  float* out = (float*)d_out;
  float* att = out + (size_t)LQS * DIN;

  char* ws = (char*)d_ws;
  ushort_t* qhb = (ushort_t*)(ws + (size_t)0);
  ushort_t* khb = (ushort_t*)(ws + ((size_t)8 << 20));
  ushort_t* vhb = (ushort_t*)(ws + ((size_t)16 << 20));
  ushort_t* vtb = (ushort_t*)(ws + ((size_t)24 << 20));
  ushort_t* ctx = (ushort_t*)(ws + ((size_t)32 << 20));
  ushort_t* qb = (ushort_t*)(ws + ((size_t)40 << 20));
  ushort_t* kb = (ushort_t*)(ws + ((size_t)48 << 20));
  ushort_t* vb = (ushort_t*)(ws + ((size_t)56 << 20));
  ushort_t* Wqt = (ushort_t*)(ws + ((size_t)64 << 20));
  ushort_t* Wkt = (ushort_t*)(ws + ((size_t)66 << 20));
  ushort_t* Wvt = (ushort_t*)(ws + ((size_t)68 << 20));
  ushort_t* Wot = (ushort_t*)(ws + ((size_t)70 << 20));
  float* rsbuf = (float*)(ws + ((size_t)72 << 20));  // [4][16][4096] f32 = 1MB

  Cvt3 c3;
  c3.src[0] = q; c3.src[1] = k; c3.src[2] = v;
  c3.dst[0] = qb; c3.dst[1] = kb; c3.dst[2] = vb;
  cvt_kernel<<<dim3(LQS * DIN / 8 / 256, 3), 256, 0, stream>>>(c3);

  TW4 w4;
  w4.W[0] = Wq; w4.W[1] = Wk; w4.W[2] = Wv; w4.W[3] = Wo;
  w4.Wt[0] = Wqt; w4.Wt[1] = Wkt; w4.Wt[2] = Wvt; w4.Wt[3] = Wot;
  transpose_w<<<dim3(16, 16, 4), 256, 0, stream>>>(w4);

  Batch3 pb;
  pb.A[0] = qb; pb.A[1] = kb; pb.A[2] = vb;
  pb.Bt[0] = Wqt; pb.Bt[1] = Wkt; pb.Bt[2] = Wvt;
  pb.bias[0] = bq; pb.bias[1] = bk; pb.bias[2] = bv;
  pb.C[0] = qhb; pb.C[1] = khb; pb.C[2] = vhb;
  pb.scale[0] = TAU_S * LOG2E; pb.scale[1] = 1.0f; pb.scale[2] = 1.0f;
  gemm_nt<false><<<768, 256, 0, stream>>>(pb);

  rowsum_kernel<<<1024, 256, 0, stream>>>(qhb, khb, rsbuf);

  transpose_v<<<dim3(64, 16), 256, 0, stream>>>(vhb, vtb);

  attn_kernel<<<512, 256, 0, stream>>>(qhb, khb, vtb, rsbuf, att, ctx);

  Batch3 ob;
  ob.A[0] = ctx; ob.A[1] = ctx; ob.A[2] = ctx;
  ob.Bt[0] = Wot; ob.Bt[1] = Wot; ob.Bt[2] = Wot;
  ob.bias[0] = bo; ob.bias[1] = bo; ob.bias[2] = bo;
  ob.C[0] = out; ob.C[1] = out; ob.C[2] = out;
  ob.scale[0] = 1.0f; ob.scale[1] = 1.0f; ob.scale[2] = 1.0f;
  gemm_nt<true><<<256, 256, 0, stream>>>(ob);
}